// Round 18
// baseline (97.350 us; speedup 1.0000x reference)
//
#include <hip/hip_runtime.h>
#include <hip/hip_fp16.h>
#include <math.h>

#define NA_ 10000
#define NM_ 150000
#define B_  4
#define NS_ 4
#define NMAX_ 32
#define NO_ 4
#define H1_ 4
#define H2_ 38
#define PI_F 3.14159265358979323846f

// ---- ws layout ----
#define CSN_OFF   ((size_t)0)
#define CSN_BYTES ((size_t)B_ * NA_ * NMAX_ * 4)            // 5,120,000
#define ST_OFF    (CSN_OFF + CSN_BYTES)
#define ST_BYTES  ((size_t)B_ * (NA_ + 1) * 4 + 64)
#define E_OFF     (ST_OFF + ST_BYTES)
#define E_BYTES   (((size_t)B_ * NM_ + 64) * NMAX_ * 2)     // fp16 E + slack
#define WS_NEED_E (E_OFF + E_BYTES)

__device__ __forceinline__ float fast_tanh(float x) {
    float t = __expf(2.0f * x);
    return 1.0f - __fdividef(2.0f, t + 1.0f);
}

template <int CTRL>
__device__ __forceinline__ float dpp_ror_add(float v) {
    int r = __builtin_amdgcn_update_dpp(0, __float_as_int(v), CTRL, 0xF, 0xF, true);
    return v + __int_as_float(r);
}
__device__ __forceinline__ float half_reduce32(float v) {
    v = dpp_ror_add<0x121>(v);
    v = dpp_ror_add<0x122>(v);
    v = dpp_ror_add<0x124>(v);
    v = dpp_ror_add<0x128>(v);
    int s = __builtin_amdgcn_ds_swizzle(__float_as_int(v), 0x401F); // xor 16
    return v + __int_as_float(s);
}

// ---------------------------------------------------------------------------
// Kernel 0: segment starts from sorted iidx.
// ---------------------------------------------------------------------------
__global__ void starts_kernel(const int* __restrict__ iidx, int* __restrict__ starts) {
    int p = blockIdx.x * blockDim.x + threadIdx.x;
    if (p >= B_ * NM_) return;
    int b = p / NM_, pl = p - b * NM_;
    const int* ii = iidx + (size_t)b * NM_;
    int* st = starts + (size_t)b * (NA_ + 1);
    int cur = ii[pl];
    int prev = (pl == 0) ? -1 : ii[pl - 1];
    for (int a = prev + 1; a <= cur; ++a) st[a] = pl;
    if (pl == NM_ - 1) {
        for (int a = cur + 1; a <= NA_; ++a) st[a] = NM_;
    }
}

// ---------------------------------------------------------------------------
// prep0: DENSE pair-parallel E writer. Half-wave = ONE pair, lane = n.
// dist/fcut computed redundantly across the 32 lanes (VALU-parallel);
// alpha/rs register-selected per lane; one coalesced 64B fp16 store.
// No segment logic, no wasted slots, no register arrays -> (256,8).
// ---------------------------------------------------------------------------
__global__ __launch_bounds__(256, 8) void prep0_kernel(
    const float* __restrict__ disp, const int* __restrict__ jidx,
    const float* __restrict__ alpha, const float* __restrict__ rsp,
    const int* __restrict__ sorted_numbers, unsigned short* __restrict__ E)
{
    int tid = threadIdx.x;
    int lane = tid & 63;
    int h = lane >> 5, n = lane & 31;
    int gp = blockIdx.x * 8 + (tid >> 6) * 2 + h;   // pair slot in [0, B*NM)
    if (gp >= B_ * NM_) return;

    float al0 = alpha[n],      al1 = alpha[32 + n];
    float al2 = alpha[64 + n], al3 = alpha[96 + n];
    float rv0 = rsp[n],        rv1 = rsp[32 + n];
    float rv2 = rsp[64 + n],   rv3 = rsp[96 + n];

    int j = jidx[gp];
    int b = gp / NM_;
    int jat = sorted_numbers[(size_t)b * NA_ * 0 + j];   // j indexes [0,NA)
    const float* dp = disp + (size_t)gp * 3;
    float x = dp[0], y = dp[1], z = dp[2];
    float dist = sqrtf(x * x + y * y + z * z);
    float c = __cosf(dist * (PI_F / 6.0f));
    float fc = 0.25f * (c + 1.f) * (c + 1.f);
    bool s0 = (jat & 1) != 0, s1 = (jat & 2) != 0;
    float av = s1 ? (s0 ? al3 : al2) : (s0 ? al1 : al0);
    float rv = s1 ? (s0 ? rv3 : rv2) : (s0 ? rv1 : rv0);
    float dd = dist - rv;
    float Ef = fc * __expf(av * dd * dd);
    E[(size_t)gp * NMAX_ + n] = __half_as_ushort(__float2half_rn(Ef));
}

// ---------------------------------------------------------------------------
// pass0_light: light KK (E * spv-select + 4 fma) + DPP reduce + shfl-MLP.
// One wave = TWO atoms (half-wave each, lane = n). rec.w carries jat.
// ---------------------------------------------------------------------------
__global__ __launch_bounds__(256, 4) void pass0_light_kernel(
    const float* __restrict__ disp, const int* __restrict__ jidx,
    const float* __restrict__ spp, const float* __restrict__ op,
    const float* __restrict__ w1, const float* __restrict__ b1,
    const float* __restrict__ w2, const float* __restrict__ b2,
    const float* __restrict__ w3, const float* __restrict__ b3,
    const int* __restrict__ sorted_numbers, const int* __restrict__ starts,
    const unsigned short* __restrict__ E, float* __restrict__ csn2)
{
    __shared__ float4 lds_rec[4][2][32];
    int tid = threadIdx.x;
    int wv = tid >> 6;
    int wave = blockIdx.x * 4 + wv;
    int lane = tid & 63;
    int h = lane >> 5, n = lane & 31;
    int g = wave * 2 + h;
    if (g >= B_ * NA_) return;
    int b = g / NA_, a = g - b * NA_;

    const int* st = starts + b * (NA_ + 1);
    int p0 = st[a], p1 = st[a + 1];
    int seg = p1 - p0;
    int oseg = __shfl_xor(seg, 32);
    int mseg = (seg > oseg) ? seg : oseg;

    const int* jjb = jidx + (size_t)b * NM_;
    const float* dpb = disp + (size_t)b * NM_ * 3;

    int pk = p0 + n;
    if (pk > NM_ - 1) pk = NM_ - 1;
    int jmine = jjb[pk];
    int jatm = sorted_numbers[jmine];
    float sx = dpb[pk * 3 + 0];
    float sy = dpb[pk * 3 + 1];
    float sz = dpb[pk * 3 + 2];
    lds_rec[wv][h][n] = make_float4(sx, sy, sz, __int_as_float(jatm));
    const float4* lp = &lds_rec[wv][h][0];

    float sp0 = spp[n], sp1 = spp[32 + n], sp2 = spp[64 + n], sp3 = spp[96 + n];

    float W0[NO_], W1[NO_];
#pragma unroll
    for (int o = 0; o < NO_; ++o) {
        W0[o] = op[(0 * NMAX_ + n) * NO_ + o];   // op[0][0]
        W1[o] = op[(1 * NMAX_ + n) * NO_ + o];   // op[0][1]
    }

    const unsigned short* Erd = E + ((size_t)b * NM_ + p0) * NMAX_ + n;
    unsigned short r[32];
#define LDR(k) r[(k)] = Erd[(k) * NMAX_];
#define LDR8(k0) LDR(k0) LDR((k0)+1) LDR((k0)+2) LDR((k0)+3) \
                 LDR((k0)+4) LDR((k0)+5) LDR((k0)+6) LDR((k0)+7)
    LDR8(0)
    if (mseg > 8)  { LDR8(8) }  else { r[8]=r[9]=r[10]=r[11]=r[12]=r[13]=r[14]=r[15]=0; }
    if (mseg > 16) { LDR8(16) } else { r[16]=r[17]=r[18]=r[19]=r[20]=r[21]=r[22]=r[23]=0; }
    if (mseg > 24) { LDR8(24) } else { r[24]=r[25]=r[26]=r[27]=r[28]=r[29]=r[30]=r[31]=0; }
#undef LDR8
#undef LDR

    float acc0 = 0.f, acc1 = 0.f, acc2 = 0.f, acc3 = 0.f;
#define KK(k) {                                                              \
    float4 q_ = lp[(k)];                                                     \
    int jat_ = __float_as_int(q_.w);                                         \
    bool s0_ = (jat_ & 1) != 0;                                              \
    bool s1_ = (jat_ & 2) != 0;                                              \
    float cv_ = s1_ ? (s0_ ? sp3 : sp2) : (s0_ ? sp1 : sp0);                 \
    float coef_ = __half2float(__ushort_as_half(r[(k)])) * cv_;              \
    coef_ = ((k) < seg) ? coef_ : 0.f;                                       \
    acc0 += coef_;                                                           \
    acc1 = fmaf(coef_, q_.x, acc1);                                          \
    acc2 = fmaf(coef_, q_.y, acc2);                                          \
    acc3 = fmaf(coef_, q_.z, acc3);                                          \
}
#define KK4(k0) if (mseg > (k0)) { KK(k0) KK((k0)+1) KK((k0)+2) KK((k0)+3) }
    KK4(0) KK4(4) KK4(8) KK4(12) KK4(16) KK4(20) KK4(24) KK4(28)
#undef KK4
#undef KK

    // rare tail: segments longer than 32 pairs
    for (int p = p0 + 32; p < p1; ++p) {
        int j = jjb[p];
        float x = dpb[p * 3 + 0], y = dpb[p * 3 + 1], z = dpb[p * 3 + 2];
        int jat = sorted_numbers[j];
        float Ef = __half2float(__ushort_as_half(
            E[((size_t)b * NM_ + p) * NMAX_ + n]));
        bool s0 = (jat & 1) != 0, s1 = (jat & 2) != 0;
        float cv = s1 ? (s0 ? sp3 : sp2) : (s0 ? sp1 : sp0);
        float coef = Ef * cv;
        acc0 += coef;
        acc1 = fmaf(coef, x, acc1);
        acc2 = fmaf(coef, y, acc2);
        acc3 = fmaf(coef, z, acc3);
    }

    float t[4][NO_];
#pragma unroll
    for (int o = 0; o < NO_; ++o) {
        t[0][o] = W0[o] * acc0;
        t[1][o] = W1[o] * acc1;
        t[2][o] = W1[o] * acc2;
        t[3][o] = W1[o] * acc3;
    }
#pragma unroll
    for (int l = 0; l < 4; ++l)
#pragma unroll
        for (int o = 0; o < NO_; ++o)
            t[l][o] = half_reduce32(t[l][o]);

    float rho[NO_];
#pragma unroll
    for (int o = 0; o < NO_; ++o)
        rho[o] = t[0][o] * t[0][o] + t[1][o] * t[1][o] +
                 t[2][o] * t[2][o] + t[3][o] * t[3][o];

    int hb = lane & 32;

    // MLP: rho(4) -> h1(4,tanh) -> h2(38,tanh) -> 32 (r15 shfl version)
    float h1v[H1_];
#pragma unroll
    for (int k = 0; k < H1_; ++k) {
        float s = b1[k];
#pragma unroll
        for (int o = 0; o < NO_; ++o) s = fmaf(rho[o], w1[o * H1_ + k], s);
        h1v[k] = fast_tanh(s);
    }
    float sa = b2[n];
    int jbi = 32 + (n < 6 ? n : 5);
    float sb = b2[jbi];
#pragma unroll
    for (int k = 0; k < H1_; ++k) {
        sa = fmaf(h1v[k], w2[k * H2_ + n], sa);
        sb = fmaf(h1v[k], w2[k * H2_ + jbi], sb);
    }
    float hva = fast_tanh(sa);
    float hvb = fast_tanh(sb);
    float on = b3[n];
#pragma unroll
    for (int j2 = 0; j2 < 32; ++j2) {
        float hj = __shfl(hva, hb + j2);
        on = fmaf(hj, w3[j2 * NMAX_ + n], on);
    }
#pragma unroll
    for (int j2 = 0; j2 < 6; ++j2) {
        float hj = __shfl(hvb, hb + j2);
        on = fmaf(hj, w3[(32 + j2) * NMAX_ + n], on);
    }
    int aat = sorted_numbers[a];
    bool t0b = (aat & 1) != 0, t1b = (aat & 2) != 0;
    float basev = t1b ? (t0b ? sp3 : sp2) : (t0b ? sp1 : sp0);
    csn2[(size_t)g * NMAX_ + n] = basev + on;
}

// ---------------------------------------------------------------------------
// pass1: identical to round-15's light pass1. rec.w carries j.
// ---------------------------------------------------------------------------
__global__ __launch_bounds__(256, 4) void pass1_kernel(
    const float* __restrict__ disp, const int* __restrict__ jidx,
    const float* __restrict__ op, const int* __restrict__ starts,
    const float* __restrict__ csn2, const unsigned short* __restrict__ E,
    float* __restrict__ out)
{
    __shared__ float4 lds_rec[4][2][32];
    int tid = threadIdx.x;
    int wv = tid >> 6;
    int wave = blockIdx.x * 4 + wv;
    int lane = tid & 63;
    int h = lane >> 5, n = lane & 31;
    int g = wave * 2 + h;
    if (g >= B_ * NA_) return;
    int b = g / NA_, a = g - b * NA_;

    const int* st = starts + b * (NA_ + 1);
    int p0 = st[a], p1 = st[a + 1];
    int seg = p1 - p0;
    int oseg = __shfl_xor(seg, 32);
    int mseg = (seg > oseg) ? seg : oseg;

    const int* jjb = jidx + (size_t)b * NM_;
    const float* dpb = disp + (size_t)b * NM_ * 3;
    const float* csb = csn2 + (size_t)b * NA_ * NMAX_;

    int pk = p0 + n;
    if (pk > NM_ - 1) pk = NM_ - 1;
    int jmine = jjb[pk];
    float sx = dpb[pk * 3 + 0];
    float sy = dpb[pk * 3 + 1];
    float sz = dpb[pk * 3 + 2];
    lds_rec[wv][h][n] = make_float4(sx, sy, sz, __int_as_float(jmine));
    const float4* lp = &lds_rec[wv][h][0];
    const int* lpi = (const int*)lp;

    float W0[NO_], W1[NO_];
#pragma unroll
    for (int o = 0; o < NO_; ++o) {
        W0[o] = op[(2 * NMAX_ + n) * NO_ + o];   // op[1][0]
        W1[o] = op[(3 * NMAX_ + n) * NO_ + o];   // op[1][1]
    }

    const unsigned short* Erd = E + ((size_t)b * NM_ + p0) * NMAX_ + n;

    float cj[32];
    unsigned short r[32];
#define LC(k) { int j_ = lpi[(k) * 4 + 3];                                   \
                cj[(k)] = csb[(size_t)j_ * NMAX_ + n]; }
#define LC8(k0) LC(k0) LC((k0)+1) LC((k0)+2) LC((k0)+3) \
                LC((k0)+4) LC((k0)+5) LC((k0)+6) LC((k0)+7)
    LC8(0)
    if (mseg > 8)  { LC8(8) }  else { cj[8]=cj[9]=cj[10]=cj[11]=cj[12]=cj[13]=cj[14]=cj[15]=0.f; }
    if (mseg > 16) { LC8(16) } else { cj[16]=cj[17]=cj[18]=cj[19]=cj[20]=cj[21]=cj[22]=cj[23]=0.f; }
    if (mseg > 24) { LC8(24) } else { cj[24]=cj[25]=cj[26]=cj[27]=cj[28]=cj[29]=cj[30]=cj[31]=0.f; }
#undef LC8
#undef LC
#define LDR(k) r[(k)] = Erd[(k) * NMAX_];
#define LDR8(k0) LDR(k0) LDR((k0)+1) LDR((k0)+2) LDR((k0)+3) \
                 LDR((k0)+4) LDR((k0)+5) LDR((k0)+6) LDR((k0)+7)
    LDR8(0)
    if (mseg > 8)  { LDR8(8) }  else { r[8]=r[9]=r[10]=r[11]=r[12]=r[13]=r[14]=r[15]=0; }
    if (mseg > 16) { LDR8(16) } else { r[16]=r[17]=r[18]=r[19]=r[20]=r[21]=r[22]=r[23]=0; }
    if (mseg > 24) { LDR8(24) } else { r[24]=r[25]=r[26]=r[27]=r[28]=r[29]=r[30]=r[31]=0; }
#undef LDR8
#undef LDR

    float acc0 = 0.f, acc1 = 0.f, acc2 = 0.f, acc3 = 0.f;
#define KK(k) {                                                              \
    float4 q_ = lp[(k)];                                                     \
    float coef_ = __half2float(__ushort_as_half(r[(k)])) * cj[(k)];          \
    coef_ = ((k) < seg) ? coef_ : 0.f;                                       \
    acc0 += coef_;                                                           \
    acc1 = fmaf(coef_, q_.x, acc1);                                          \
    acc2 = fmaf(coef_, q_.y, acc2);                                          \
    acc3 = fmaf(coef_, q_.z, acc3);                                          \
}
#define KK4(k0) if (mseg > (k0)) { KK(k0) KK((k0)+1) KK((k0)+2) KK((k0)+3) }
    KK4(0) KK4(4) KK4(8) KK4(12) KK4(16) KK4(20) KK4(24) KK4(28)
#undef KK4
#undef KK

    for (int p = p0 + 32; p < p1; ++p) {
        int j = jjb[p];
        float x = dpb[p * 3 + 0], y = dpb[p * 3 + 1], z = dpb[p * 3 + 2];
        float Ef = __half2float(__ushort_as_half(
            E[((size_t)b * NM_ + p) * NMAX_ + n]));
        float coef = Ef * csb[(size_t)j * NMAX_ + n];
        acc0 += coef;
        acc1 = fmaf(coef, x, acc1);
        acc2 = fmaf(coef, y, acc2);
        acc3 = fmaf(coef, z, acc3);
    }

    float t[4][NO_];
#pragma unroll
    for (int o = 0; o < NO_; ++o) {
        t[0][o] = W0[o] * acc0;
        t[1][o] = W1[o] * acc1;
        t[2][o] = W1[o] * acc2;
        t[3][o] = W1[o] * acc3;
    }
#pragma unroll
    for (int l = 0; l < 4; ++l)
#pragma unroll
        for (int o = 0; o < NO_; ++o)
            t[l][o] = half_reduce32(t[l][o]);

    float rho[NO_];
#pragma unroll
    for (int o = 0; o < NO_; ++o)
        rho[o] = t[0][o] * t[0][o] + t[1][o] * t[1][o] +
                 t[2][o] * t[2][o] + t[3][o] * t[3][o];

    if (n == 0) {
        *reinterpret_cast<float4*>(out + (size_t)g * NO_) =
            make_float4(rho[0], rho[1], rho[2], rho[3]);
    }
}

// ---------------------------------------------------------------------------
// Fallback (ws too small for E): round-15 fused kernel (register selects).
// ---------------------------------------------------------------------------
template <int PASS>
__global__ __launch_bounds__(256, 4) void fb_pass_kernel(
    const float* __restrict__ disp, const int* __restrict__ jidx,
    const float* __restrict__ alpha, const float* __restrict__ rsp,
    const float* __restrict__ spp, const float* __restrict__ op,
    const float* __restrict__ w1, const float* __restrict__ b1,
    const float* __restrict__ w2, const float* __restrict__ b2,
    const float* __restrict__ w3, const float* __restrict__ b3,
    const int* __restrict__ sorted_numbers, const int* __restrict__ starts,
    float* __restrict__ csn2, float* __restrict__ out)
{
    __shared__ float4 lds_rec[4][2][32];
    __shared__ float2 lds_df[4][2][32];
    int tid = threadIdx.x;
    int wv = tid >> 6;
    int wave = blockIdx.x * 4 + wv;
    int lane = tid & 63;
    int h = lane >> 5, n = lane & 31;
    int g = wave * 2 + h;
    if (g >= B_ * NA_) return;
    int b = g / NA_, a = g - b * NA_;

    const int* st = starts + b * (NA_ + 1);
    int p0 = st[a], p1 = st[a + 1];
    int seg = p1 - p0;
    int oseg = __shfl_xor(seg, 32);
    int mseg = (seg > oseg) ? seg : oseg;

    const int* jjb = jidx + (size_t)b * NM_;
    const float* dpb = disp + (size_t)b * NM_ * 3;
    const float* csb = csn2 + (size_t)b * NA_ * NMAX_;

    int pk = p0 + n;
    if (pk > NM_ - 1) pk = NM_ - 1;
    int jmine = jjb[pk];
    float sx = dpb[pk * 3 + 0];
    float sy = dpb[pk * 3 + 1];
    float sz = dpb[pk * 3 + 2];
    int jatm = sorted_numbers[jmine];
    float sd = sqrtf(sx * sx + sy * sy + sz * sz);
    float sc = __cosf(sd * (PI_F / 6.0f));
    float sfc = 0.25f * (sc + 1.f) * (sc + 1.f);
    lds_rec[wv][h][n] = make_float4(sx, sy, sz,
                                    __int_as_float(jmine | (jatm << 14)));
    lds_df[wv][h][n] = make_float2(sd, sfc);
    const float4* lp = &lds_rec[wv][h][0];
    const int* lpi = (const int*)lp;
    const float4* ldf4 = reinterpret_cast<const float4*>(&lds_df[wv][h][0]);

    float al0 = alpha[n],      al1 = alpha[32 + n];
    float al2 = alpha[64 + n], al3 = alpha[96 + n];
    float rv0 = rsp[n],        rv1 = rsp[32 + n];
    float rv2 = rsp[64 + n],   rv3 = rsp[96 + n];
    float sp0 = spp[n], sp1 = spp[32 + n], sp2 = spp[64 + n], sp3 = spp[96 + n];

    const float* opb = op + (size_t)PASS * 2 * NMAX_ * NO_;
    float W0[NO_], W1[NO_];
#pragma unroll
    for (int o = 0; o < NO_; ++o) {
        W0[o] = opb[(0 * NMAX_ + n) * NO_ + o];
        W1[o] = opb[(1 * NMAX_ + n) * NO_ + o];
    }

    float cj[32];
    if constexpr (PASS == 1) {
#define LC(k) { int w_ = lpi[(k) * 4 + 3] & 0x3fff;                          \
                cj[(k)] = csb[(size_t)w_ * NMAX_ + n]; }
#define LC8(k0) LC(k0) LC((k0)+1) LC((k0)+2) LC((k0)+3) \
                LC((k0)+4) LC((k0)+5) LC((k0)+6) LC((k0)+7)
        LC8(0)
        if (mseg > 8)  { LC8(8) }  else { cj[8]=cj[9]=cj[10]=cj[11]=cj[12]=cj[13]=cj[14]=cj[15]=0.f; }
        if (mseg > 16) { LC8(16) } else { cj[16]=cj[17]=cj[18]=cj[19]=cj[20]=cj[21]=cj[22]=cj[23]=0.f; }
        if (mseg > 24) { LC8(24) } else { cj[24]=cj[25]=cj[26]=cj[27]=cj[28]=cj[29]=cj[30]=cj[31]=0.f; }
#undef LC8
#undef LC
    }

    float acc0 = 0.f, acc1 = 0.f, acc2 = 0.f, acc3 = 0.f;
#define KKF(k, DD, FF) {                                                     \
    float4 q_ = lp[(k)];                                                     \
    int w_ = __float_as_int(q_.w);                                           \
    bool s0_ = (w_ & (1 << 14)) != 0;                                        \
    bool s1_ = (w_ & (1 << 15)) != 0;                                        \
    float av_ = s1_ ? (s0_ ? al3 : al2) : (s0_ ? al1 : al0);                 \
    float rv_ = s1_ ? (s0_ ? rv3 : rv2) : (s0_ ? rv1 : rv0);                 \
    float dd_ = (DD) - rv_;                                                  \
    float e_ = __expf(av_ * dd_ * dd_);                                      \
    float Ef_ = e_ * (FF);                                                   \
    float cv_;                                                               \
    if constexpr (PASS == 0) {                                               \
        cv_ = s1_ ? (s0_ ? sp3 : sp2) : (s0_ ? sp1 : sp0);                   \
    } else {                                                                 \
        cv_ = cj[(k)];                                                       \
    }                                                                        \
    float coef_ = Ef_ * cv_;                                                 \
    coef_ = ((k) < seg) ? coef_ : 0.f;                                       \
    acc0 += coef_;                                                           \
    acc1 = fmaf(coef_, q_.x, acc1);                                          \
    acc2 = fmaf(coef_, q_.y, acc2);                                          \
    acc3 = fmaf(coef_, q_.z, acc3);                                          \
}
#define KK4F(k0) if (mseg > (k0)) {                                          \
    float4 dA_ = ldf4[(k0) >> 1];                                            \
    float4 dB_ = ldf4[((k0) >> 1) + 1];                                      \
    KKF(k0, dA_.x, dA_.y) KKF((k0)+1, dA_.z, dA_.w)                          \
    KKF((k0)+2, dB_.x, dB_.y) KKF((k0)+3, dB_.z, dB_.w) }
    KK4F(0) KK4F(4) KK4F(8) KK4F(12) KK4F(16) KK4F(20) KK4F(24) KK4F(28)
#undef KK4F
#undef KKF

    for (int p = p0 + 32; p < p1; ++p) {
        int j = jjb[p];
        float x = dpb[p * 3 + 0], y = dpb[p * 3 + 1], z = dpb[p * 3 + 2];
        int jat = sorted_numbers[j];
        float dist = sqrtf(x * x + y * y + z * z);
        float c = __cosf(dist * (PI_F / 6.0f));
        float fc = 0.25f * (c + 1.f) * (c + 1.f);
        bool s0 = (jat & 1) != 0, s1 = (jat & 2) != 0;
        float av = s1 ? (s0 ? al3 : al2) : (s0 ? al1 : al0);
        float rv = s1 ? (s0 ? rv3 : rv2) : (s0 ? rv1 : rv0);
        float dd = dist - rv;
        float Ef = fc * __expf(av * dd * dd);
        float cv;
        if constexpr (PASS == 0)
            cv = s1 ? (s0 ? sp3 : sp2) : (s0 ? sp1 : sp0);
        else
            cv = csb[(size_t)j * NMAX_ + n];
        float coef = Ef * cv;
        acc0 += coef;
        acc1 = fmaf(coef, x, acc1);
        acc2 = fmaf(coef, y, acc2);
        acc3 = fmaf(coef, z, acc3);
    }

    float t[4][NO_];
#pragma unroll
    for (int o = 0; o < NO_; ++o) {
        t[0][o] = W0[o] * acc0;
        t[1][o] = W1[o] * acc1;
        t[2][o] = W1[o] * acc2;
        t[3][o] = W1[o] * acc3;
    }
#pragma unroll
    for (int l = 0; l < 4; ++l)
#pragma unroll
        for (int o = 0; o < NO_; ++o)
            t[l][o] = half_reduce32(t[l][o]);

    float rho[NO_];
#pragma unroll
    for (int o = 0; o < NO_; ++o)
        rho[o] = t[0][o] * t[0][o] + t[1][o] * t[1][o] +
                 t[2][o] * t[2][o] + t[3][o] * t[3][o];

    int hb = lane & 32;

    if constexpr (PASS == 1) {
        if (n == 0) {
            *reinterpret_cast<float4*>(out + (size_t)g * NO_) =
                make_float4(rho[0], rho[1], rho[2], rho[3]);
        }
    } else {
        float h1v[H1_];
#pragma unroll
        for (int k = 0; k < H1_; ++k) {
            float s = b1[k];
#pragma unroll
            for (int o = 0; o < NO_; ++o) s = fmaf(rho[o], w1[o * H1_ + k], s);
            h1v[k] = fast_tanh(s);
        }
        float sa = b2[n];
        int jbi = 32 + (n < 6 ? n : 5);
        float sb = b2[jbi];
#pragma unroll
        for (int k = 0; k < H1_; ++k) {
            sa = fmaf(h1v[k], w2[k * H2_ + n], sa);
            sb = fmaf(h1v[k], w2[k * H2_ + jbi], sb);
        }
        float hva = fast_tanh(sa);
        float hvb = fast_tanh(sb);
        float on = b3[n];
#pragma unroll
        for (int j2 = 0; j2 < 32; ++j2) {
            float hj = __shfl(hva, hb + j2);
            on = fmaf(hj, w3[j2 * NMAX_ + n], on);
        }
#pragma unroll
        for (int j2 = 0; j2 < 6; ++j2) {
            float hj = __shfl(hvb, hb + j2);
            on = fmaf(hj, w3[(32 + j2) * NMAX_ + n], on);
        }
        int aat = sorted_numbers[a];
        bool t0b = (aat & 1) != 0, t1b = (aat & 2) != 0;
        float basev = t1b ? (t0b ? sp3 : sp2) : (t0b ? sp1 : sp0);
        csn2[(size_t)g * NMAX_ + n] = basev + on;
    }
}

extern "C" void kernel_launch(void* const* d_in, const int* in_sizes, int n_in,
                              void* d_out, int out_size, void* d_ws, size_t ws_size,
                              hipStream_t stream) {
    const float* disp = (const float*)d_in[0];
    const float* alpha = (const float*)d_in[1];
    const float* rsp = (const float*)d_in[2];
    const float* spp = (const float*)d_in[3];
    const float* op = (const float*)d_in[4];
    const float* w1 = (const float*)d_in[5];
    const float* b1 = (const float*)d_in[6];
    const float* w2 = (const float*)d_in[7];
    const float* b2 = (const float*)d_in[8];
    const float* w3 = (const float*)d_in[9];
    const float* b3 = (const float*)d_in[10];
    const int* iidx = (const int*)d_in[11];
    const int* jidx = (const int*)d_in[12];
    const int* sn = (const int*)d_in[13];
    float* out = (float*)d_out;

    float* csn2 = (float*)((char*)d_ws + CSN_OFF);
    int* starts = (int*)((char*)d_ws + ST_OFF);
    unsigned short* E = (unsigned short*)((char*)d_ws + E_OFF);

    int nthr = B_ * NM_;
    starts_kernel<<<(nthr + 255) / 256, 256, 0, stream>>>(iidx, starts);

    int ablocks = (B_ * NA_) / 8;            // 2 atoms/wave, 4 waves/block
    if (ws_size >= WS_NEED_E) {
        int pblocks = (B_ * NM_) / 8;        // 2 pairs/wave, 4 waves/block
        prep0_kernel<<<pblocks, 256, 0, stream>>>(disp, jidx, alpha, rsp, sn, E);
        pass0_light_kernel<<<ablocks, 256, 0, stream>>>(disp, jidx, spp, op,
                                                        w1, b1, w2, b2, w3, b3,
                                                        sn, starts, E, csn2);
        pass1_kernel<<<ablocks, 256, 0, stream>>>(disp, jidx, op, starts,
                                                  csn2, E, out);
    } else {
        fb_pass_kernel<0><<<ablocks, 256, 0, stream>>>(disp, jidx, alpha, rsp,
                                                       spp, op, w1, b1, w2, b2,
                                                       w3, b3, sn, starts,
                                                       csn2, out);
        fb_pass_kernel<1><<<ablocks, 256, 0, stream>>>(disp, jidx, alpha, rsp,
                                                       spp, op, w1, b1, w2, b2,
                                                       w3, b3, sn, starts,
                                                       csn2, out);
    }
}

// Round 19
// 64.137 us; speedup vs baseline: 1.5178x; 1.5178x over previous
//
#include <hip/hip_runtime.h>
#include <hip/hip_fp16.h>
#include <math.h>

#define NA_ 10000
#define NM_ 150000
#define B_  4
#define NS_ 4
#define NMAX_ 32
#define NO_ 4
#define H1_ 4
#define H2_ 38
#define PI_F 3.14159265358979323846f
#define LOG2E_F 1.44269504088896f

// ---- ws layout ----
#define CSN_OFF   ((size_t)0)
#define CSN_BYTES ((size_t)B_ * NA_ * NMAX_ * 4)            // 5,120,000
#define ST_OFF    (CSN_OFF + CSN_BYTES)
#define ST_BYTES  ((size_t)B_ * (NA_ + 1) * 4 + 64)
#define E_OFF     (ST_OFF + ST_BYTES)
#define E_BYTES   (((size_t)B_ * NM_ + 64) * NMAX_ * 2)     // fp16 E + slack
#define WS_NEED_E (E_OFF + E_BYTES)

__device__ __forceinline__ float fast_tanh(float x) {
    float t = __expf(2.0f * x);
    return 1.0f - __fdividef(2.0f, t + 1.0f);
}

template <int CTRL>
__device__ __forceinline__ float dpp_ror_add(float v) {
    int r = __builtin_amdgcn_update_dpp(0, __float_as_int(v), CTRL, 0xF, 0xF, true);
    return v + __int_as_float(r);
}
__device__ __forceinline__ float half_reduce32(float v) {
    v = dpp_ror_add<0x121>(v);
    v = dpp_ror_add<0x122>(v);
    v = dpp_ror_add<0x124>(v);
    v = dpp_ror_add<0x128>(v);
    int s = __builtin_amdgcn_ds_swizzle(__float_as_int(v), 0x401F); // xor 16
    return v + __int_as_float(s);
}

// ---------------------------------------------------------------------------
// Kernel 0: segment starts from sorted iidx.
// ---------------------------------------------------------------------------
__global__ void starts_kernel(const int* __restrict__ iidx, int* __restrict__ starts) {
    int p = blockIdx.x * blockDim.x + threadIdx.x;
    if (p >= B_ * NM_) return;
    int b = p / NM_, pl = p - b * NM_;
    const int* ii = iidx + (size_t)b * NM_;
    int* st = starts + (size_t)b * (NA_ + 1);
    int cur = ii[pl];
    int prev = (pl == 0) ? -1 : ii[pl - 1];
    for (int a = prev + 1; a <= cur; ++a) st[a] = pl;
    if (pl == NM_ - 1) {
        for (int a = cur + 1; a <= NA_; ++a) st[a] = NM_;
    }
}

// ---------------------------------------------------------------------------
// pass: one wave = TWO atoms (half-wave each, lane = n). Round-15 structure.
// Fused KK (PASS0 / fallback): tab2 LDS float2 (alpha*log2e, rs) lookup via
// ONE ds_read_b64 (8B stride = 2-way = free) + native exp2f; sp via cndmask.
// PASS0+USE_E stores E fp16 (guarded k<seg). PASS1 USE_E: light KK = E*cj.
// Reduction: DPP rotate + xor16 swizzle. MLP epilogue: r15 shfl version.
// ---------------------------------------------------------------------------
template <int PASS, int USE_E>
__global__ __launch_bounds__(256, 4) void pass_kernel(
    const float* __restrict__ disp, const int* __restrict__ jidx,
    const float* __restrict__ alpha, const float* __restrict__ rsp,
    const float* __restrict__ spp, const float* __restrict__ op,
    const float* __restrict__ w1, const float* __restrict__ b1,
    const float* __restrict__ w2, const float* __restrict__ b2,
    const float* __restrict__ w3, const float* __restrict__ b3,
    const int* __restrict__ sorted_numbers, const int* __restrict__ starts,
    float* __restrict__ csn2, unsigned short* __restrict__ E,
    float* __restrict__ out)
{
    __shared__ float4 lds_rec[4][2][32];
    __shared__ float2 lds_df[4][2][32];
    __shared__ float2 tab2[NS_ * NMAX_];

    int tid = threadIdx.x;
    if constexpr (PASS == 0 || !USE_E) {
        if (tid < NS_ * NMAX_)
            tab2[tid] = make_float2(alpha[tid] * LOG2E_F, rsp[tid]);
        __syncthreads();
    }

    int wv = tid >> 6;
    int wave = blockIdx.x * 4 + wv;
    int lane = tid & 63;
    int h = lane >> 5, n = lane & 31;
    int g = wave * 2 + h;
    if (g >= B_ * NA_) return;
    int b = g / NA_, a = g - b * NA_;

    const int* st = starts + b * (NA_ + 1);
    int p0 = st[a], p1 = st[a + 1];
    int seg = p1 - p0;
    int oseg = __shfl_xor(seg, 32);
    int mseg = (seg > oseg) ? seg : oseg;   // wave-uniform

    const int* jjb = jidx + (size_t)b * NM_;
    const float* dpb = disp + (size_t)b * NM_ * 3;
    const float* csb = csn2 + (size_t)b * NA_ * NMAX_;

    // ---- stage: lane n handles pair p0+n (clamped in-image) ----
    int pk = p0 + n;
    if (pk > NM_ - 1) pk = NM_ - 1;
    int jmine = jjb[pk];
    float sx = dpb[pk * 3 + 0];
    float sy = dpb[pk * 3 + 1];
    float sz = dpb[pk * 3 + 2];
    if constexpr (PASS == 0 || !USE_E) {
        int jatm = sorted_numbers[jmine];
        float sd = sqrtf(sx * sx + sy * sy + sz * sz);
        float sc = __cosf(sd * (PI_F / 6.0f));
        float sfc = 0.25f * (sc + 1.f) * (sc + 1.f);
        lds_rec[wv][h][n] = make_float4(sx, sy, sz,
                                        __int_as_float(jmine | (jatm << 14)));
        lds_df[wv][h][n] = make_float2(sd, sfc);
    } else {
        lds_rec[wv][h][n] = make_float4(sx, sy, sz, __int_as_float(jmine));
    }
    const float4* lp = &lds_rec[wv][h][0];
    const int* lpi = (const int*)lp;
    const float4* ldf4 = reinterpret_cast<const float4*>(&lds_df[wv][h][0]);
    const float2* tab2n = tab2 + n;

    float sp0 = spp[n], sp1 = spp[32 + n], sp2 = spp[64 + n], sp3 = spp[96 + n];

    const float* opb = op + (size_t)PASS * 2 * NMAX_ * NO_;
    float W0[NO_], W1[NO_];
#pragma unroll
    for (int o = 0; o < NO_; ++o) {
        W0[o] = opb[(0 * NMAX_ + n) * NO_ + o];
        W1[o] = opb[(1 * NMAX_ + n) * NO_ + o];
    }

    // per-lane E pointer (element units): E[(b*NM + p0 + k)*32 + n]
    unsigned short* Ebl = nullptr;
    const unsigned short* Erd = nullptr;
    if constexpr (USE_E) {
        Ebl = E + ((size_t)b * NM_ + p0) * NMAX_ + n;
        Erd = Ebl;
    }

    // (PASS1) upfront csn2 gathers (both variants) and E loads (USE_E)
    float cj[32];
    unsigned short r[32];
    if constexpr (PASS == 1) {
#define LC(k) { int w_ = lpi[(k) * 4 + 3];                                   \
                int j_ = USE_E ? w_ : (w_ & 0x3fff);                         \
                cj[(k)] = csb[(size_t)j_ * NMAX_ + n]; }
#define LC8(k0) LC(k0) LC((k0)+1) LC((k0)+2) LC((k0)+3) \
                LC((k0)+4) LC((k0)+5) LC((k0)+6) LC((k0)+7)
        LC8(0)
        if (mseg > 8)  { LC8(8) }  else { cj[8]=cj[9]=cj[10]=cj[11]=cj[12]=cj[13]=cj[14]=cj[15]=0.f; }
        if (mseg > 16) { LC8(16) } else { cj[16]=cj[17]=cj[18]=cj[19]=cj[20]=cj[21]=cj[22]=cj[23]=0.f; }
        if (mseg > 24) { LC8(24) } else { cj[24]=cj[25]=cj[26]=cj[27]=cj[28]=cj[29]=cj[30]=cj[31]=0.f; }
#undef LC8
#undef LC
        if constexpr (USE_E) {
#define LDR(k) r[(k)] = Erd[(k) * NMAX_];
#define LDR8(k0) LDR(k0) LDR((k0)+1) LDR((k0)+2) LDR((k0)+3) \
                 LDR((k0)+4) LDR((k0)+5) LDR((k0)+6) LDR((k0)+7)
            LDR8(0)
            if (mseg > 8)  { LDR8(8) }  else { r[8]=r[9]=r[10]=r[11]=r[12]=r[13]=r[14]=r[15]=0; }
            if (mseg > 16) { LDR8(16) } else { r[16]=r[17]=r[18]=r[19]=r[20]=r[21]=r[22]=r[23]=0; }
            if (mseg > 24) { LDR8(24) } else { r[24]=r[25]=r[26]=r[27]=r[28]=r[29]=r[30]=r[31]=0; }
#undef LDR8
#undef LDR
        }
    }

    float acc0 = 0.f, acc1 = 0.f, acc2 = 0.f, acc3 = 0.f;

    if constexpr (PASS == 1 && USE_E) {
        // light KK: coef = E*cj
#define KK(k) {                                                              \
    float4 q_ = lp[(k)];                                                     \
    float coef_ = __half2float(__ushort_as_half(r[(k)])) * cj[(k)];          \
    coef_ = ((k) < seg) ? coef_ : 0.f;                                       \
    acc0 += coef_;                                                           \
    acc1 = fmaf(coef_, q_.x, acc1);                                          \
    acc2 = fmaf(coef_, q_.y, acc2);                                          \
    acc3 = fmaf(coef_, q_.z, acc3);                                          \
}
#define KK4(k0) if (mseg > (k0)) { KK(k0) KK((k0)+1) KK((k0)+2) KK((k0)+3) }
        KK4(0) KK4(4) KK4(8) KK4(12) KK4(16) KK4(20) KK4(24) KK4(28)
#undef KK4
#undef KK
    } else {
        // fused KK: tab2 b64 lookup + exp2 (+ guarded E store on PASS0&&USE_E)
#define KKF(k, DD, FF) {                                                     \
    float4 q_ = lp[(k)];                                                     \
    int w_ = __float_as_int(q_.w);                                           \
    int jat_ = (w_ >> 14) & 3;                                               \
    float2 ar_ = tab2n[jat_ * NMAX_];      /* ds_read_b64, 2-way = free */   \
    float dd_ = (DD) - ar_.y;                                                \
    float e_ = exp2f(ar_.x * dd_ * dd_);                                     \
    float Ef_ = e_ * (FF);                                                   \
    if constexpr (PASS == 0 && USE_E) {                                      \
        if ((k) < seg)                                                       \
            Ebl[(k) * NMAX_] = __half_as_ushort(__float2half_rn(Ef_));       \
    }                                                                        \
    float cv_;                                                               \
    if constexpr (PASS == 0) {                                               \
        bool s0_ = (w_ & (1 << 14)) != 0;                                    \
        bool s1_ = (w_ & (1 << 15)) != 0;                                    \
        cv_ = s1_ ? (s0_ ? sp3 : sp2) : (s0_ ? sp1 : sp0);                   \
    } else {                                                                 \
        cv_ = cj[(k)];                                                       \
    }                                                                        \
    float coef_ = Ef_ * cv_;                                                 \
    coef_ = ((k) < seg) ? coef_ : 0.f;                                       \
    acc0 += coef_;                                                           \
    acc1 = fmaf(coef_, q_.x, acc1);                                          \
    acc2 = fmaf(coef_, q_.y, acc2);                                          \
    acc3 = fmaf(coef_, q_.z, acc3);                                          \
}
#define KK4F(k0) if (mseg > (k0)) {                                          \
    float4 dA_ = ldf4[(k0) >> 1];                                            \
    float4 dB_ = ldf4[((k0) >> 1) + 1];                                      \
    KKF(k0, dA_.x, dA_.y) KKF((k0)+1, dA_.z, dA_.w)                          \
    KKF((k0)+2, dB_.x, dB_.y) KKF((k0)+3, dB_.z, dB_.w) }
        KK4F(0) KK4F(4) KK4F(8) KK4F(12) KK4F(16) KK4F(20) KK4F(24) KK4F(28)
#undef KK4F
#undef KKF
    }

    // rare tail: segments longer than 32 pairs
    for (int p = p0 + 32; p < p1; ++p) {
        int j = jjb[p];
        float x = dpb[p * 3 + 0], y = dpb[p * 3 + 1], z = dpb[p * 3 + 2];
        float coef;
        if constexpr (PASS == 1 && USE_E) {
            float Ef = __half2float(__ushort_as_half(
                E[((size_t)b * NM_ + p) * NMAX_ + n]));
            coef = Ef * csb[(size_t)j * NMAX_ + n];
        } else {
            int jat = sorted_numbers[j];
            float dist = sqrtf(x * x + y * y + z * z);
            float c = __cosf(dist * (PI_F / 6.0f));
            float fc = 0.25f * (c + 1.f) * (c + 1.f);
            float2 ar = tab2n[(jat & 3) * NMAX_];
            float dd = dist - ar.y;
            float Ef = fc * exp2f(ar.x * dd * dd);
            if constexpr (PASS == 0 && USE_E)
                E[((size_t)b * NM_ + p) * NMAX_ + n] =
                    __half_as_ushort(__float2half_rn(Ef));
            float cv;
            if constexpr (PASS == 0) {
                bool s0 = (jat & 1) != 0, s1 = (jat & 2) != 0;
                cv = s1 ? (s0 ? sp3 : sp2) : (s0 ? sp1 : sp0);
            } else {
                cv = csb[(size_t)j * NMAX_ + n];
            }
            coef = Ef * cv;
        }
        acc0 += coef;
        acc1 = fmaf(coef, x, acc1);
        acc2 = fmaf(coef, y, acc2);
        acc3 = fmaf(coef, z, acc3);
    }

    // t[l][o] reduction over the 32-lane half via DPP rotate-reduce
    float t[4][NO_];
#pragma unroll
    for (int o = 0; o < NO_; ++o) {
        t[0][o] = W0[o] * acc0;
        t[1][o] = W1[o] * acc1;
        t[2][o] = W1[o] * acc2;
        t[3][o] = W1[o] * acc3;
    }
#pragma unroll
    for (int l = 0; l < 4; ++l)
#pragma unroll
        for (int o = 0; o < NO_; ++o)
            t[l][o] = half_reduce32(t[l][o]);

    float rho[NO_];
#pragma unroll
    for (int o = 0; o < NO_; ++o)
        rho[o] = t[0][o] * t[0][o] + t[1][o] * t[1][o] +
                 t[2][o] * t[2][o] + t[3][o] * t[3][o];

    int hb = lane & 32;

    if constexpr (PASS == 1) {
        if (n == 0) {
            *reinterpret_cast<float4*>(out + (size_t)g * NO_) =
                make_float4(rho[0], rho[1], rho[2], rho[3]);
        }
    } else {
        // MLP: rho(4) -> h1(4,tanh) -> h2(38,tanh) -> 32 (r15 shfl version)
        float h1v[H1_];
#pragma unroll
        for (int k = 0; k < H1_; ++k) {
            float s = b1[k];
#pragma unroll
            for (int o = 0; o < NO_; ++o) s = fmaf(rho[o], w1[o * H1_ + k], s);
            h1v[k] = fast_tanh(s);
        }
        float sa = b2[n];
        int jbi = 32 + (n < 6 ? n : 5);
        float sb = b2[jbi];
#pragma unroll
        for (int k = 0; k < H1_; ++k) {
            sa = fmaf(h1v[k], w2[k * H2_ + n], sa);
            sb = fmaf(h1v[k], w2[k * H2_ + jbi], sb);
        }
        float hva = fast_tanh(sa);
        float hvb = fast_tanh(sb);
        float on = b3[n];
#pragma unroll
        for (int j2 = 0; j2 < 32; ++j2) {
            float hj = __shfl(hva, hb + j2);
            on = fmaf(hj, w3[j2 * NMAX_ + n], on);
        }
#pragma unroll
        for (int j2 = 0; j2 < 6; ++j2) {
            float hj = __shfl(hvb, hb + j2);
            on = fmaf(hj, w3[(32 + j2) * NMAX_ + n], on);
        }
        int aat = sorted_numbers[a];
        bool t0b = (aat & 1) != 0, t1b = (aat & 2) != 0;
        float basev = t1b ? (t0b ? sp3 : sp2) : (t0b ? sp1 : sp0);
        csn2[(size_t)g * NMAX_ + n] = basev + on;
    }
}

extern "C" void kernel_launch(void* const* d_in, const int* in_sizes, int n_in,
                              void* d_out, int out_size, void* d_ws, size_t ws_size,
                              hipStream_t stream) {
    const float* disp = (const float*)d_in[0];
    const float* alpha = (const float*)d_in[1];
    const float* rsp = (const float*)d_in[2];
    const float* spp = (const float*)d_in[3];
    const float* op = (const float*)d_in[4];
    const float* w1 = (const float*)d_in[5];
    const float* b1 = (const float*)d_in[6];
    const float* w2 = (const float*)d_in[7];
    const float* b2 = (const float*)d_in[8];
    const float* w3 = (const float*)d_in[9];
    const float* b3 = (const float*)d_in[10];
    const int* iidx = (const int*)d_in[11];
    const int* jidx = (const int*)d_in[12];
    const int* sn = (const int*)d_in[13];
    float* out = (float*)d_out;

    float* csn2 = (float*)((char*)d_ws + CSN_OFF);
    int* starts = (int*)((char*)d_ws + ST_OFF);
    unsigned short* E = (unsigned short*)((char*)d_ws + E_OFF);

    int nthr = B_ * NM_;
    starts_kernel<<<(nthr + 255) / 256, 256, 0, stream>>>(iidx, starts);

    int ablocks = (B_ * NA_) / 8;          // 2 atoms/wave, 4 waves/block
    if (ws_size >= WS_NEED_E) {
        pass_kernel<0, 1><<<ablocks, 256, 0, stream>>>(disp, jidx, alpha, rsp,
                                                       spp, op, w1, b1, w2, b2,
                                                       w3, b3, sn, starts,
                                                       csn2, E, out);
        pass_kernel<1, 1><<<ablocks, 256, 0, stream>>>(disp, jidx, alpha, rsp,
                                                       spp, op, w1, b1, w2, b2,
                                                       w3, b3, sn, starts,
                                                       csn2, E, out);
    } else {
        pass_kernel<0, 0><<<ablocks, 256, 0, stream>>>(disp, jidx, alpha, rsp,
                                                       spp, op, w1, b1, w2, b2,
                                                       w3, b3, sn, starts,
                                                       csn2, E, out);
        pass_kernel<1, 0><<<ablocks, 256, 0, stream>>>(disp, jidx, alpha, rsp,
                                                       spp, op, w1, b1, w2, b2,
                                                       w3, b3, sn, starts,
                                                       csn2, E, out);
    }
}

// Round 20
// 62.258 us; speedup vs baseline: 1.5637x; 1.0302x over previous
//
#include <hip/hip_runtime.h>
#include <hip/hip_fp16.h>
#include <math.h>

#define NA_ 10000
#define NM_ 150000
#define B_  4
#define NS_ 4
#define NMAX_ 32
#define NO_ 4
#define H1_ 4
#define H2_ 38
#define PI_F 3.14159265358979323846f

// ---- ws layout ----
#define CSN_OFF   ((size_t)0)
#define CSN_BYTES ((size_t)B_ * NA_ * NMAX_ * 4)            // 5,120,000
#define ST_OFF    (CSN_OFF + CSN_BYTES)
#define ST_BYTES  ((size_t)B_ * (NA_ + 1) * 4 + 64)
#define E_OFF     (ST_OFF + ST_BYTES)
#define E_BYTES   (((size_t)B_ * NM_ + 64) * NMAX_ * 2)     // fp16 E + slack
#define WS_NEED_E (E_OFF + E_BYTES)

__device__ __forceinline__ float fast_tanh(float x) {
    float t = __expf(2.0f * x);
    return 1.0f - __fdividef(2.0f, t + 1.0f);
}

// DPP rotate-add within the 16-lane row (VALU, no DS traffic).
// CTRL must be an immediate: template parameter.
template <int CTRL>
__device__ __forceinline__ float dpp_ror_add(float v) {
    int r = __builtin_amdgcn_update_dpp(0, __float_as_int(v), CTRL, 0xF, 0xF, true);
    return v + __int_as_float(r);
}
// Sum over the 32-lane half: 4 DPP row-rotations (row sum) + 1 ds_swizzle xor16.
__device__ __forceinline__ float half_reduce32(float v) {
    v = dpp_ror_add<0x121>(v);   // row_ror:1
    v = dpp_ror_add<0x122>(v);   // row_ror:2
    v = dpp_ror_add<0x124>(v);   // row_ror:4
    v = dpp_ror_add<0x128>(v);   // row_ror:8  -> each 16-row holds its sum
    int s = __builtin_amdgcn_ds_swizzle(__float_as_int(v), 0x401F); // xor 16
    return v + __int_as_float(s);
}

// ---------------------------------------------------------------------------
// Kernel 0: segment starts from sorted iidx.
// ---------------------------------------------------------------------------
__global__ void starts_kernel(const int* __restrict__ iidx, int* __restrict__ starts) {
    int p = blockIdx.x * blockDim.x + threadIdx.x;
    if (p >= B_ * NM_) return;
    int b = p / NM_, pl = p - b * NM_;
    const int* ii = iidx + (size_t)b * NM_;
    int* st = starts + (size_t)b * (NA_ + 1);
    int cur = ii[pl];
    int prev = (pl == 0) ? -1 : ii[pl - 1];
    for (int a = prev + 1; a <= cur; ++a) st[a] = pl;
    if (pl == NM_ - 1) {
        for (int a = cur + 1; a <= NA_; ++a) st[a] = NM_;
    }
}

// ---------------------------------------------------------------------------
// pass: one wave = TWO atoms (half-wave each, lane = n). Round-12 structure
// with DS-traffic cuts: DPP reduction (80->16 DS/wave) and paired df reads.
// PASS0 (and fallback PASS1 !USE_E): fused radial compute; PASS0+USE_E
//   stores E=fc*exp(...) fp16 (exec-guarded k<seg).
// PASS1 USE_E: light staging, 32 E loads + 32 csn2 gathers upfront,
//   KK = cvt*cj + 4 fma.
// ---------------------------------------------------------------------------
template <int PASS, int USE_E>
__global__ __launch_bounds__(256, 4) void pass_kernel(
    const float* __restrict__ disp, const int* __restrict__ jidx,
    const float* __restrict__ alpha, const float* __restrict__ rsp,
    const float* __restrict__ spp, const float* __restrict__ op,
    const float* __restrict__ w1, const float* __restrict__ b1,
    const float* __restrict__ w2, const float* __restrict__ b2,
    const float* __restrict__ w3, const float* __restrict__ b3,
    const int* __restrict__ sorted_numbers, const int* __restrict__ starts,
    float* __restrict__ csn2, unsigned short* __restrict__ E,
    float* __restrict__ out)
{
    __shared__ float4 lds_rec[4][2][32];
    __shared__ float2 lds_df[4][2][32];
    int wv = threadIdx.x >> 6;
    int wave = blockIdx.x * 4 + wv;
    int lane = threadIdx.x & 63;
    int h = lane >> 5, n = lane & 31;
    int g = wave * 2 + h;
    if (g >= B_ * NA_) return;
    int b = g / NA_, a = g - b * NA_;

    const int* st = starts + b * (NA_ + 1);
    int p0 = st[a], p1 = st[a + 1];
    int seg = p1 - p0;
    int oseg = __shfl_xor(seg, 32);
    int mseg = (seg > oseg) ? seg : oseg;   // wave-uniform

    const int* jjb = jidx + (size_t)b * NM_;
    const float* dpb = disp + (size_t)b * NM_ * 3;
    const float* csb = csn2 + (size_t)b * NA_ * NMAX_;

    // ---- stage: lane n handles pair p0+n (clamped in-image) ----
    int pk = p0 + n;
    if (pk > NM_ - 1) pk = NM_ - 1;
    int jmine = jjb[pk];
    float sx = dpb[pk * 3 + 0];
    float sy = dpb[pk * 3 + 1];
    float sz = dpb[pk * 3 + 2];
    if constexpr (PASS == 0 || !USE_E) {
        int jatm = sorted_numbers[jmine];
        float sd = sqrtf(sx * sx + sy * sy + sz * sz);
        float sc = __cosf(sd * (PI_F / 6.0f));
        float sfc = 0.25f * (sc + 1.f) * (sc + 1.f);
        lds_rec[wv][h][n] = make_float4(sx, sy, sz,
                                        __int_as_float(jmine | (jatm << 14)));
        lds_df[wv][h][n] = make_float2(sd, sfc);
    } else {
        lds_rec[wv][h][n] = make_float4(sx, sy, sz, __int_as_float(jmine));
    }
    const float4* lp = &lds_rec[wv][h][0];
    const int* lpi = (const int*)lp;
    const float4* ldf4 = reinterpret_cast<const float4*>(&lds_df[wv][h][0]);

    // per-n tables in registers
    float al0 = alpha[n],      al1 = alpha[32 + n];
    float al2 = alpha[64 + n], al3 = alpha[96 + n];
    float rv0 = rsp[n],        rv1 = rsp[32 + n];
    float rv2 = rsp[64 + n],   rv3 = rsp[96 + n];
    float sp0 = spp[n], sp1 = spp[32 + n], sp2 = spp[64 + n], sp3 = spp[96 + n];

    const float* opb = op + (size_t)PASS * 2 * NMAX_ * NO_;
    float W0[NO_], W1[NO_];
#pragma unroll
    for (int o = 0; o < NO_; ++o) {
        W0[o] = opb[(0 * NMAX_ + n) * NO_ + o];
        W1[o] = opb[(1 * NMAX_ + n) * NO_ + o];
    }

    // per-lane E pointer (element units): E[(b*NM + p0 + k)*32 + n]
    unsigned short* Ebl = nullptr;
    const unsigned short* Erd = nullptr;
    if constexpr (USE_E) {
        Ebl = E + ((size_t)b * NM_ + p0) * NMAX_ + n;
        Erd = Ebl;
    }

    // (PASS1) upfront csn2 gathers (both variants) and E loads (USE_E)
    float cj[32];
    unsigned short r[32];
    if constexpr (PASS == 1) {
#define LC(k) { int w_ = lpi[(k) * 4 + 3];                                   \
                int j_ = USE_E ? w_ : (w_ & 0x3fff);                         \
                cj[(k)] = csb[(size_t)j_ * NMAX_ + n]; }
#define LC8(k0) LC(k0) LC((k0)+1) LC((k0)+2) LC((k0)+3) \
                LC((k0)+4) LC((k0)+5) LC((k0)+6) LC((k0)+7)
        LC8(0)
        if (mseg > 8)  { LC8(8) }  else { cj[8]=cj[9]=cj[10]=cj[11]=cj[12]=cj[13]=cj[14]=cj[15]=0.f; }
        if (mseg > 16) { LC8(16) } else { cj[16]=cj[17]=cj[18]=cj[19]=cj[20]=cj[21]=cj[22]=cj[23]=0.f; }
        if (mseg > 24) { LC8(24) } else { cj[24]=cj[25]=cj[26]=cj[27]=cj[28]=cj[29]=cj[30]=cj[31]=0.f; }
#undef LC8
#undef LC
        if constexpr (USE_E) {
#define LDR(k) r[(k)] = Erd[(k) * NMAX_];
#define LDR8(k0) LDR(k0) LDR((k0)+1) LDR((k0)+2) LDR((k0)+3) \
                 LDR((k0)+4) LDR((k0)+5) LDR((k0)+6) LDR((k0)+7)
            LDR8(0)
            if (mseg > 8)  { LDR8(8) }  else { r[8]=r[9]=r[10]=r[11]=r[12]=r[13]=r[14]=r[15]=0; }
            if (mseg > 16) { LDR8(16) } else { r[16]=r[17]=r[18]=r[19]=r[20]=r[21]=r[22]=r[23]=0; }
            if (mseg > 24) { LDR8(24) } else { r[24]=r[25]=r[26]=r[27]=r[28]=r[29]=r[30]=r[31]=0; }
#undef LDR8
#undef LDR
        }
    }

    float acc0 = 0.f, acc1 = 0.f, acc2 = 0.f, acc3 = 0.f;

    if constexpr (PASS == 1 && USE_E) {
        // light KK: coef = E*cj
#define KK(k) {                                                              \
    float4 q_ = lp[(k)];                                                     \
    float coef_ = __half2float(__ushort_as_half(r[(k)])) * cj[(k)];          \
    coef_ = ((k) < seg) ? coef_ : 0.f;                                       \
    acc0 += coef_;                                                           \
    acc1 = fmaf(coef_, q_.x, acc1);                                          \
    acc2 = fmaf(coef_, q_.y, acc2);                                          \
    acc3 = fmaf(coef_, q_.z, acc3);                                          \
}
#define KK4(k0) if (mseg > (k0)) { KK(k0) KK((k0)+1) KK((k0)+2) KK((k0)+3) }
        KK4(0) KK4(4) KK4(8) KK4(12) KK4(16) KK4(20) KK4(24) KK4(28)
#undef KK4
#undef KK
    } else {
        // fused KK: selects + exp (+ E store on PASS0&&USE_E); df via paired b128
#define KKF(k, DD, FF) {                                                     \
    float4 q_ = lp[(k)];                                                     \
    int w_ = __float_as_int(q_.w);                                           \
    bool s0_ = (w_ & (1 << 14)) != 0;                                        \
    bool s1_ = (w_ & (1 << 15)) != 0;                                        \
    float av_ = s1_ ? (s0_ ? al3 : al2) : (s0_ ? al1 : al0);                 \
    float rv_ = s1_ ? (s0_ ? rv3 : rv2) : (s0_ ? rv1 : rv0);                 \
    float dd_ = (DD) - rv_;                                                  \
    float e_ = __expf(av_ * dd_ * dd_);                                      \
    float Ef_ = e_ * (FF);                                                   \
    if constexpr (PASS == 0 && USE_E) {                                      \
        if ((k) < seg)                                                       \
            Ebl[(k) * NMAX_] = __half_as_ushort(__float2half_rn(Ef_));       \
    }                                                                        \
    float cv_;                                                               \
    if constexpr (PASS == 0) {                                               \
        cv_ = s1_ ? (s0_ ? sp3 : sp2) : (s0_ ? sp1 : sp0);                   \
    } else {                                                                 \
        cv_ = cj[(k)];                                                       \
    }                                                                        \
    float coef_ = Ef_ * cv_;                                                 \
    coef_ = ((k) < seg) ? coef_ : 0.f;                                       \
    acc0 += coef_;                                                           \
    acc1 = fmaf(coef_, q_.x, acc1);                                          \
    acc2 = fmaf(coef_, q_.y, acc2);                                          \
    acc3 = fmaf(coef_, q_.z, acc3);                                          \
}
#define KK4F(k0) if (mseg > (k0)) {                                          \
    float4 dA_ = ldf4[(k0) >> 1];                                            \
    float4 dB_ = ldf4[((k0) >> 1) + 1];                                      \
    KKF(k0, dA_.x, dA_.y) KKF((k0)+1, dA_.z, dA_.w)                          \
    KKF((k0)+2, dB_.x, dB_.y) KKF((k0)+3, dB_.z, dB_.w) }
        KK4F(0) KK4F(4) KK4F(8) KK4F(12) KK4F(16) KK4F(20) KK4F(24) KK4F(28)
#undef KK4F
#undef KKF
    }

    // rare tail: segments longer than 32 pairs
    for (int p = p0 + 32; p < p1; ++p) {
        int j = jjb[p];
        float x = dpb[p * 3 + 0], y = dpb[p * 3 + 1], z = dpb[p * 3 + 2];
        float coef;
        if constexpr (PASS == 1 && USE_E) {
            float Ef = __half2float(__ushort_as_half(
                E[((size_t)b * NM_ + p) * NMAX_ + n]));
            coef = Ef * csb[(size_t)j * NMAX_ + n];
        } else {
            int jat = sorted_numbers[j];
            float dist = sqrtf(x * x + y * y + z * z);
            float c = __cosf(dist * (PI_F / 6.0f));
            float fc = 0.25f * (c + 1.f) * (c + 1.f);
            bool s0 = (jat & 1) != 0, s1 = (jat & 2) != 0;
            float av = s1 ? (s0 ? al3 : al2) : (s0 ? al1 : al0);
            float rv = s1 ? (s0 ? rv3 : rv2) : (s0 ? rv1 : rv0);
            float dd = dist - rv;
            float Ef = fc * __expf(av * dd * dd);
            if constexpr (PASS == 0 && USE_E)
                E[((size_t)b * NM_ + p) * NMAX_ + n] =
                    __half_as_ushort(__float2half_rn(Ef));
            float cv;
            if constexpr (PASS == 0)
                cv = s1 ? (s0 ? sp3 : sp2) : (s0 ? sp1 : sp0);
            else
                cv = csb[(size_t)j * NMAX_ + n];
            coef = Ef * cv;
        }
        acc0 += coef;
        acc1 = fmaf(coef, x, acc1);
        acc2 = fmaf(coef, y, acc2);
        acc3 = fmaf(coef, z, acc3);
    }

    // t[l][o] reduction over the 32-lane half via DPP rotate-reduce
    float t[4][NO_];
#pragma unroll
    for (int o = 0; o < NO_; ++o) {
        t[0][o] = W0[o] * acc0;
        t[1][o] = W1[o] * acc1;
        t[2][o] = W1[o] * acc2;
        t[3][o] = W1[o] * acc3;
    }
#pragma unroll
    for (int l = 0; l < 4; ++l)
#pragma unroll
        for (int o = 0; o < NO_; ++o)
            t[l][o] = half_reduce32(t[l][o]);

    float rho[NO_];
#pragma unroll
    for (int o = 0; o < NO_; ++o)
        rho[o] = t[0][o] * t[0][o] + t[1][o] * t[1][o] +
                 t[2][o] * t[2][o] + t[3][o] * t[3][o];

    int hb = lane & 32;

    if constexpr (PASS == 1) {
        if (n == 0) {
            *reinterpret_cast<float4*>(out + (size_t)g * NO_) =
                make_float4(rho[0], rho[1], rho[2], rho[3]);
        }
    } else {
        // MLP: rho(4) -> h1(4,tanh) -> h2(38,tanh) -> 32, per atom-half
        float h1v[H1_];
#pragma unroll
        for (int k = 0; k < H1_; ++k) {
            float s = b1[k];
#pragma unroll
            for (int o = 0; o < NO_; ++o) s = fmaf(rho[o], w1[o * H1_ + k], s);
            h1v[k] = fast_tanh(s);
        }
        float sa = b2[n];
        int jbi = 32 + (n < 6 ? n : 5);
        float sb = b2[jbi];
#pragma unroll
        for (int k = 0; k < H1_; ++k) {
            sa = fmaf(h1v[k], w2[k * H2_ + n], sa);
            sb = fmaf(h1v[k], w2[k * H2_ + jbi], sb);
        }
        float hva = fast_tanh(sa);
        float hvb = fast_tanh(sb);
        float on = b3[n];
#pragma unroll
        for (int j2 = 0; j2 < 32; ++j2) {
            float hj = __shfl(hva, hb + j2);
            on = fmaf(hj, w3[j2 * NMAX_ + n], on);
        }
#pragma unroll
        for (int j2 = 0; j2 < 6; ++j2) {
            float hj = __shfl(hvb, hb + j2);
            on = fmaf(hj, w3[(32 + j2) * NMAX_ + n], on);
        }
        int aat = sorted_numbers[a];
        bool t0b = (aat & 1) != 0, t1b = (aat & 2) != 0;
        float basev = t1b ? (t0b ? sp3 : sp2) : (t0b ? sp1 : sp0);
        csn2[(size_t)g * NMAX_ + n] = basev + on;
    }
}

extern "C" void kernel_launch(void* const* d_in, const int* in_sizes, int n_in,
                              void* d_out, int out_size, void* d_ws, size_t ws_size,
                              hipStream_t stream) {
    const float* disp = (const float*)d_in[0];
    const float* alpha = (const float*)d_in[1];
    const float* rsp = (const float*)d_in[2];
    const float* spp = (const float*)d_in[3];
    const float* op = (const float*)d_in[4];
    const float* w1 = (const float*)d_in[5];
    const float* b1 = (const float*)d_in[6];
    const float* w2 = (const float*)d_in[7];
    const float* b2 = (const float*)d_in[8];
    const float* w3 = (const float*)d_in[9];
    const float* b3 = (const float*)d_in[10];
    const int* iidx = (const int*)d_in[11];
    const int* jidx = (const int*)d_in[12];
    const int* sn = (const int*)d_in[13];
    float* out = (float*)d_out;

    float* csn2 = (float*)((char*)d_ws + CSN_OFF);
    int* starts = (int*)((char*)d_ws + ST_OFF);
    unsigned short* E = (unsigned short*)((char*)d_ws + E_OFF);

    int nthr = B_ * NM_;
    starts_kernel<<<(nthr + 255) / 256, 256, 0, stream>>>(iidx, starts);

    int ablocks = (B_ * NA_) / 8;          // 2 atoms/wave, 4 waves/block
    if (ws_size >= WS_NEED_E) {
        pass_kernel<0, 1><<<ablocks, 256, 0, stream>>>(disp, jidx, alpha, rsp,
                                                       spp, op, w1, b1, w2, b2,
                                                       w3, b3, sn, starts,
                                                       csn2, E, out);
        pass_kernel<1, 1><<<ablocks, 256, 0, stream>>>(disp, jidx, alpha, rsp,
                                                       spp, op, w1, b1, w2, b2,
                                                       w3, b3, sn, starts,
                                                       csn2, E, out);
    } else {
        pass_kernel<0, 0><<<ablocks, 256, 0, stream>>>(disp, jidx, alpha, rsp,
                                                       spp, op, w1, b1, w2, b2,
                                                       w3, b3, sn, starts,
                                                       csn2, E, out);
        pass_kernel<1, 0><<<ablocks, 256, 0, stream>>>(disp, jidx, alpha, rsp,
                                                       spp, op, w1, b1, w2, b2,
                                                       w3, b3, sn, starts,
                                                       csn2, E, out);
    }
}